// Round 3
// baseline (80.948 us; speedup 1.0000x reference)
//
#include <hip/hip_runtime.h>
#include <math.h>

#define BB 32
#define TT 512
#define FF 512
#define HH 1024
#define CC 1000
#define QQ (4*HH)    // 4096 gate columns
#define FCB 8        // fc columns per block

// ---------------- Stage 1a: h0 contribution ----------------
// grid = (4 gates, CH_H chunks), block = 256. Each thread: 4 cols (float4),
// JCH = 1024/CH_H rows. Partial -> hp[ch*QQ + gate*HH + t*4 ..].
template<int JCH>
__global__ __launch_bounds__(256) void k_h0part(
    const float* __restrict__ h0,
    const float* __restrict__ wf, const float* __restrict__ wi,
    const float* __restrict__ wc, const float* __restrict__ wo,
    float* __restrict__ hp)
{
    __shared__ float h0s[JCH];
    const int t    = threadIdx.x;
    const int gate = blockIdx.x;
    const int ch   = blockIdx.y;
    const float* w = (gate==0) ? wf : (gate==1) ? wi : (gate==2) ? wc : wo;
    if (t < JCH) h0s[t] = h0[ch*JCH + t];
    __syncthreads();
    const int k4 = t*4;
    float4 s = make_float4(0.f, 0.f, 0.f, 0.f);
    #pragma unroll 8
    for (int j = 0; j < JCH; ++j) {
        const float4 wv = *(const float4*)(w + (size_t)(ch*JCH + j)*HH + k4);
        const float  hv = h0s[j];
        s.x += hv*wv.x; s.y += hv*wv.y; s.z += hv*wv.z; s.w += hv*wv.w;
    }
    *(float4*)(hp + (size_t)ch*QQ + gate*HH + k4) = s;
}

// ---------------- Stage 1b: data[:,T-1,:] contribution ----------------
// grid = (16 col-blocks, CH_D chunks), block = 256.
// Lane (t&63) -> 4 cols; wave (t>>6) -> 8 batches. JCD = 512/CH_D rows.
template<int JCD>
__global__ __launch_bounds__(256) void k_datapart(
    const float* __restrict__ data,
    const float* __restrict__ wf, const float* __restrict__ wi,
    const float* __restrict__ wc, const float* __restrict__ wo,
    float* __restrict__ dp)
{
    __shared__ float ds[BB][JCD];
    const int t    = threadIdx.x;
    const int cb   = blockIdx.x;            // 256-col block
    const int cd   = blockIdx.y;            // j-chunk
    const int gate = (cb*256) >> 10;        // uniform per block
    const int k0   = (cb*256) & (HH-1);
    const float* w = (gate==0) ? wf : (gate==1) ? wi : (gate==2) ? wc : wo;
    const int jc0  = cd*JCD;

    // stage data chunk: 32 batches x JCD floats, float4 loads
    constexpr int SL = BB*JCD/4;            // float4 slots
    for (int s = t; s < SL; s += 256) {
        const int b  = s / (JCD/4);
        const int jj = (s % (JCD/4))*4;
        const float4 v = *(const float4*)(data + (size_t)b*TT*FF + (size_t)(TT-1)*FF + jc0 + jj);
        ds[b][jj+0] = v.x; ds[b][jj+1] = v.y; ds[b][jj+2] = v.z; ds[b][jj+3] = v.w;
    }
    __syncthreads();

    const int lane = t & 63;
    const int b0   = (t >> 6) * 8;
    const int k4   = k0 + lane*4;
    float4 acc[8];
    #pragma unroll
    for (int bi = 0; bi < 8; ++bi) acc[bi] = make_float4(0.f,0.f,0.f,0.f);

    #pragma unroll 4
    for (int j = 0; j < JCD; ++j) {
        const float4 wv = *(const float4*)(w + (size_t)(HH + jc0 + j)*HH + k4);
        #pragma unroll
        for (int bi = 0; bi < 8; ++bi) {
            const float dv = ds[b0+bi][j];
            acc[bi].x += dv*wv.x; acc[bi].y += dv*wv.y;
            acc[bi].z += dv*wv.z; acc[bi].w += dv*wv.w;
        }
    }
    #pragma unroll
    for (int bi = 0; bi < 8; ++bi)
        *(float4*)(dp + ((size_t)cd*BB + b0 + bi)*QQ + cb*256 + lane*4) = acc[bi];
}

// ---------------- Stage 2: reduce partials + gates -> h_last ----------------
// grid = (HH/256 = 4, BB), block = 256.
__global__ __launch_bounds__(256) void k_cell(
    const float* __restrict__ hp, const float* __restrict__ dp,
    const float* __restrict__ c0, float* __restrict__ hlast,
    int ch_h, int ch_d)
{
    const int t = threadIdx.x;
    const int k = blockIdx.x*256 + t;
    const int b = blockIdx.y;
    float g[4];
    #pragma unroll
    for (int gi = 0; gi < 4; ++gi) {
        const int q = gi*HH + k;
        float s = 0.f;
        for (int ch = 0; ch < ch_h; ++ch) s += hp[(size_t)ch*QQ + q];
        for (int cd = 0; cd < ch_d; ++cd) s += dp[((size_t)cd*BB + b)*QQ + q];
        g[gi] = s;
    }
    const float fg = 1.f/(1.f + expf(-g[0]));
    const float ig = 1.f/(1.f + expf(-g[1]));
    const float cg = tanhf(g[2]);
    const float og = 1.f/(1.f + expf(-g[3]));
    const float c  = fg*c0[k] + ig*cg;
    hlast[(size_t)b*HH + k] = og*tanhf(c);
}

// ---------------- Stage 3a: relu(h @ fc_w^T + fc_b) -> d_out ----------------
// grid = (CC/FCB = 125), block = 256.
__global__ __launch_bounds__(256) void k_fc_gemm(
    const float* __restrict__ hlast, const float* __restrict__ fcw,
    const float* __restrict__ fcb, float* __restrict__ logits)
{
    __shared__ float hs[BB][257];
    __shared__ float wl[FCB][257];
    const int t  = threadIdx.x;
    const int c0 = blockIdx.x * FCB;
    const int b  = t & 31;
    const int cl = t >> 5;
    const int c  = c0 + cl;
    float acc = 0.f;
    #pragma unroll
    for (int kc = 0; kc < HH/256; ++kc) {
        const int k0 = kc*256;
        for (int l = t; l < BB*64; l += 256) {
            const int bb = l >> 6, kk = l & 63;
            const float4 v = *(const float4*)(hlast + (size_t)bb*HH + k0 + kk*4);
            hs[bb][kk*4+0] = v.x; hs[bb][kk*4+1] = v.y;
            hs[bb][kk*4+2] = v.z; hs[bb][kk*4+3] = v.w;
        }
        for (int l = t; l < FCB*64; l += 256) {
            const int cc = l >> 6, kk = l & 63;
            const float4 v = *(const float4*)(fcw + (size_t)(c0+cc)*HH + k0 + kk*4);
            wl[cc][kk*4+0] = v.x; wl[cc][kk*4+1] = v.y;
            wl[cc][kk*4+2] = v.z; wl[cc][kk*4+3] = v.w;
        }
        __syncthreads();
        #pragma unroll 16
        for (int k = 0; k < 256; ++k)
            acc += hs[b][k] * wl[cl][k];
        __syncthreads();
    }
    logits[(size_t)b*CC + c] = fmaxf(acc + fcb[c], 0.f);
}

// ---------------- Stage 3b: log_softmax in place on d_out ----------------
// grid = (BB), block = 256.
__global__ __launch_bounds__(256) void k_lsm(float* __restrict__ out)
{
    __shared__ float red[8];
    const int b = blockIdx.x, t = threadIdx.x;
    float v[4]; float vmax = -1e30f;
    #pragma unroll
    for (int ci = 0; ci < 4; ++ci) {
        const int c = t + ci*256;
        v[ci] = (c < CC) ? out[(size_t)b*CC + c] : -1e30f;
        vmax = fmaxf(vmax, v[ci]);
    }
    for (int o = 32; o > 0; o >>= 1) vmax = fmaxf(vmax, __shfl_down(vmax, o, 64));
    const int lane = t & 63, wid = t >> 6;
    if (lane == 0) red[wid] = vmax;
    __syncthreads();
    if (t == 0) red[4] = fmaxf(fmaxf(red[0], red[1]), fmaxf(red[2], red[3]));
    __syncthreads();
    const float m = red[4];
    float se = 0.f;
    #pragma unroll
    for (int ci = 0; ci < 4; ++ci) {
        const int c = t + ci*256;
        if (c < CC) se += expf(v[ci] - m);
    }
    for (int o = 32; o > 0; o >>= 1) se += __shfl_down(se, o, 64);
    if (lane == 0) red[wid] = se;
    __syncthreads();
    if (t == 0) red[5] = m + logf(red[0] + red[1] + red[2] + red[3]);
    __syncthreads();
    const float lse = red[5];
    #pragma unroll
    for (int ci = 0; ci < 4; ++ci) {
        const int c = t + ci*256;
        if (c < CC) out[(size_t)b*CC + c] = v[ci] - lse;
    }
}

extern "C" void kernel_launch(void* const* d_in, const int* in_sizes, int n_in,
                              void* d_out, int out_size, void* d_ws, size_t ws_size,
                              hipStream_t stream) {
    const float* data = (const float*)d_in[0];
    const float* h0   = (const float*)d_in[1];
    const float* c0   = (const float*)d_in[2];
    const float* wf   = (const float*)d_in[3];
    const float* wi   = (const float*)d_in[4];
    const float* wc   = (const float*)d_in[5];
    const float* wo   = (const float*)d_in[6];
    const float* fcw  = (const float*)d_in[7];
    const float* fcb  = (const float*)d_in[8];
    float* out = (float*)d_out;

    // Config A: CH_H=32 (JCH=32), CH_D=8 (JCD=64) -> 4.85 MB ws, 256 stage-1 blocks.
    // Config B: CH_H=8  (JCH=128), CH_D=4 (JCD=128) -> 2.36 MB ws (proven safe).
    const size_t needA = ((size_t)32*QQ + (size_t)8*BB*QQ + (size_t)BB*HH) * 4;
    const bool cfgA = (ws_size >= needA);
    const int CH_H = cfgA ? 32 : 8;
    const int CH_D = cfgA ? 8  : 4;

    float* ws = (float*)d_ws;
    float* hp = ws;                               // CH_H*QQ
    float* dp = hp + (size_t)CH_H*QQ;             // CH_D*BB*QQ
    float* hl = dp + (size_t)CH_D*BB*QQ;          // BB*HH

    if (cfgA) {
        k_h0part<32><<<dim3(4, 32), 256, 0, stream>>>(h0, wf, wi, wc, wo, hp);
        k_datapart<64><<<dim3(16, 8), 256, 0, stream>>>(data, wf, wi, wc, wo, dp);
    } else {
        k_h0part<128><<<dim3(4, 8), 256, 0, stream>>>(h0, wf, wi, wc, wo, hp);
        k_datapart<128><<<dim3(16, 4), 256, 0, stream>>>(data, wf, wi, wc, wo, dp);
    }
    k_cell<<<dim3(HH/256, BB), 256, 0, stream>>>(hp, dp, c0, hl, CH_H, CH_D);
    k_fc_gemm<<<dim3(CC/FCB), 256, 0, stream>>>(hl, fcw, fcb, out);
    k_lsm<<<dim3(BB), 256, 0, stream>>>(out);
}

// Round 4
// 46.432 us; speedup vs baseline: 1.7434x; 1.7434x over previous
//
#include <hip/hip_runtime.h>
#include <math.h>

#define BB 32
#define TT 512
#define FF 512
#define HH 1024
#define CC 1000
#define QQ (4*HH)    // 4096 gate columns
#define FCB 8        // fc columns per block

// ---------------- Stage 1a: h0 contribution ----------------
// grid = (4 gates, CH_H chunks), block = 256. Each thread: 4 cols (float4),
// JCH rows. Partial -> hp[ch*QQ + gate*HH + t*4 ..].
template<int JCH>
__global__ __launch_bounds__(256) void k_h0part(
    const float* __restrict__ h0,
    const float* __restrict__ wf, const float* __restrict__ wi,
    const float* __restrict__ wc, const float* __restrict__ wo,
    float* __restrict__ hp)
{
    __shared__ float h0s[JCH];
    const int t    = threadIdx.x;
    const int gate = blockIdx.x;
    const int ch   = blockIdx.y;
    const float* w = (gate==0) ? wf : (gate==1) ? wi : (gate==2) ? wc : wo;
    if (t < JCH) h0s[t] = h0[ch*JCH + t];
    __syncthreads();
    const int k4 = t*4;
    float4 s = make_float4(0.f, 0.f, 0.f, 0.f);
    #pragma unroll 16
    for (int j = 0; j < JCH; ++j) {
        const float4 wv = *(const float4*)(w + (size_t)(ch*JCH + j)*HH + k4);
        const float  hv = h0s[j];
        s.x += hv*wv.x; s.y += hv*wv.y; s.z += hv*wv.z; s.w += hv*wv.w;
    }
    *(float4*)(hp + (size_t)ch*QQ + gate*HH + k4) = s;
}

// ---------------- Stage 1b: data[:,T-1,:] contribution ----------------
// grid = (16 col-blocks, CH_D chunks), block = 256.
// Lane (t&63) -> 4 cols; wave (t>>6) -> 8 batches. JCD rows per chunk.
template<int JCD>
__global__ __launch_bounds__(256) void k_datapart(
    const float* __restrict__ data,
    const float* __restrict__ wf, const float* __restrict__ wi,
    const float* __restrict__ wc, const float* __restrict__ wo,
    float* __restrict__ dp)
{
    __shared__ float ds[BB][JCD];
    const int t    = threadIdx.x;
    const int cb   = blockIdx.x;            // 256-col block
    const int cd   = blockIdx.y;            // j-chunk
    const int gate = (cb*256) >> 10;        // uniform per block
    const int k0   = (cb*256) & (HH-1);
    const float* w = (gate==0) ? wf : (gate==1) ? wi : (gate==2) ? wc : wo;
    const int jc0  = cd*JCD;

    constexpr int SL = BB*JCD/4;            // float4 slots
    for (int s = t; s < SL; s += 256) {
        const int b  = s / (JCD/4);
        const int jj = (s % (JCD/4))*4;
        const float4 v = *(const float4*)(data + (size_t)b*TT*FF + (size_t)(TT-1)*FF + jc0 + jj);
        ds[b][jj+0] = v.x; ds[b][jj+1] = v.y; ds[b][jj+2] = v.z; ds[b][jj+3] = v.w;
    }
    __syncthreads();

    const int lane = t & 63;
    const int b0   = (t >> 6) * 8;
    const int k4   = k0 + lane*4;
    float4 acc[8];
    #pragma unroll
    for (int bi = 0; bi < 8; ++bi) acc[bi] = make_float4(0.f,0.f,0.f,0.f);

    #pragma unroll 16
    for (int j = 0; j < JCD; ++j) {
        const float4 wv = *(const float4*)(w + (size_t)(HH + jc0 + j)*HH + k4);
        #pragma unroll
        for (int bi = 0; bi < 8; ++bi) {
            const float dv = ds[b0+bi][j];
            acc[bi].x += dv*wv.x; acc[bi].y += dv*wv.y;
            acc[bi].z += dv*wv.z; acc[bi].w += dv*wv.w;
        }
    }
    #pragma unroll
    for (int bi = 0; bi < 8; ++bi)
        *(float4*)(dp + ((size_t)cd*BB + b0 + bi)*QQ + cb*256 + lane*4) = acc[bi];
}

// ---------------- Stage 2: reduce partials + gates -> h_last ----------------
// grid = (HH/256 = 4, BB), block = 256. Thread (g = t>>6, i = t&63) sums all
// chunks for gate g, float4 column i; LDS combine; wave 0 does the cell update.
template<int CH, int CD>
__global__ __launch_bounds__(256) void k_cell(
    const float* __restrict__ hp, const float* __restrict__ dp,
    const float* __restrict__ c0, float* __restrict__ hlast)
{
    __shared__ float4 p[4][64];
    const int t    = threadIdx.x;
    const int kblk = blockIdx.x;
    const int b    = blockIdx.y;
    const int g    = t >> 6;
    const int i    = t & 63;
    const int q    = g*HH + kblk*256 + i*4;

    float4 s = make_float4(0.f,0.f,0.f,0.f);
    #pragma unroll
    for (int ch = 0; ch < CH; ++ch) {
        const float4 v = *(const float4*)(hp + (size_t)ch*QQ + q);
        s.x += v.x; s.y += v.y; s.z += v.z; s.w += v.w;
    }
    #pragma unroll
    for (int cd = 0; cd < CD; ++cd) {
        const float4 v = *(const float4*)(dp + ((size_t)cd*BB + b)*QQ + q);
        s.x += v.x; s.y += v.y; s.z += v.z; s.w += v.w;
    }
    p[g][i] = s;
    __syncthreads();

    if (t < 64) {
        const float4 gf = p[0][t], gi = p[1][t], gc = p[2][t], go = p[3][t];
        const float4 cv = *(const float4*)(c0 + kblk*256 + t*4);
        float4 h;
        {
            const float f = 1.f/(1.f + expf(-gf.x)), ii = 1.f/(1.f + expf(-gi.x));
            const float cg = tanhf(gc.x), o = 1.f/(1.f + expf(-go.x));
            h.x = o*tanhf(f*cv.x + ii*cg);
        }
        {
            const float f = 1.f/(1.f + expf(-gf.y)), ii = 1.f/(1.f + expf(-gi.y));
            const float cg = tanhf(gc.y), o = 1.f/(1.f + expf(-go.y));
            h.y = o*tanhf(f*cv.y + ii*cg);
        }
        {
            const float f = 1.f/(1.f + expf(-gf.z)), ii = 1.f/(1.f + expf(-gi.z));
            const float cg = tanhf(gc.z), o = 1.f/(1.f + expf(-go.z));
            h.z = o*tanhf(f*cv.z + ii*cg);
        }
        {
            const float f = 1.f/(1.f + expf(-gf.w)), ii = 1.f/(1.f + expf(-gi.w));
            const float cg = tanhf(gc.w), o = 1.f/(1.f + expf(-go.w));
            h.w = o*tanhf(f*cv.w + ii*cg);
        }
        *(float4*)(hlast + (size_t)b*HH + kblk*256 + t*4) = h;
    }
}

// ---------------- Stage 3a: relu(h @ fc_w^T + fc_b) -> d_out ----------------
// grid = (CC/FCB = 125), block = 256.
__global__ __launch_bounds__(256) void k_fc_gemm(
    const float* __restrict__ hlast, const float* __restrict__ fcw,
    const float* __restrict__ fcb, float* __restrict__ logits)
{
    __shared__ float hs[BB][257];
    __shared__ float wl[FCB][257];
    const int t  = threadIdx.x;
    const int c0 = blockIdx.x * FCB;
    const int b  = t & 31;
    const int cl = t >> 5;
    const int c  = c0 + cl;
    float acc = 0.f;
    #pragma unroll
    for (int kc = 0; kc < HH/256; ++kc) {
        const int k0 = kc*256;
        for (int l = t; l < BB*64; l += 256) {
            const int bb = l >> 6, kk = l & 63;
            const float4 v = *(const float4*)(hlast + (size_t)bb*HH + k0 + kk*4);
            hs[bb][kk*4+0] = v.x; hs[bb][kk*4+1] = v.y;
            hs[bb][kk*4+2] = v.z; hs[bb][kk*4+3] = v.w;
        }
        for (int l = t; l < FCB*64; l += 256) {
            const int cc = l >> 6, kk = l & 63;
            const float4 v = *(const float4*)(fcw + (size_t)(c0+cc)*HH + k0 + kk*4);
            wl[cc][kk*4+0] = v.x; wl[cc][kk*4+1] = v.y;
            wl[cc][kk*4+2] = v.z; wl[cc][kk*4+3] = v.w;
        }
        __syncthreads();
        #pragma unroll 16
        for (int k = 0; k < 256; ++k)
            acc += hs[b][k] * wl[cl][k];
        __syncthreads();
    }
    logits[(size_t)b*CC + c] = fmaxf(acc + fcb[c], 0.f);
}

// ---------------- Stage 3b: log_softmax in place on d_out ----------------
// grid = (BB), block = 256.
__global__ __launch_bounds__(256) void k_lsm(float* __restrict__ out)
{
    __shared__ float red[8];
    const int b = blockIdx.x, t = threadIdx.x;
    float v[4]; float vmax = -1e30f;
    #pragma unroll
    for (int ci = 0; ci < 4; ++ci) {
        const int c = t + ci*256;
        v[ci] = (c < CC) ? out[(size_t)b*CC + c] : -1e30f;
        vmax = fmaxf(vmax, v[ci]);
    }
    for (int o = 32; o > 0; o >>= 1) vmax = fmaxf(vmax, __shfl_down(vmax, o, 64));
    const int lane = t & 63, wid = t >> 6;
    if (lane == 0) red[wid] = vmax;
    __syncthreads();
    if (t == 0) red[4] = fmaxf(fmaxf(red[0], red[1]), fmaxf(red[2], red[3]));
    __syncthreads();
    const float m = red[4];
    float se = 0.f;
    #pragma unroll
    for (int ci = 0; ci < 4; ++ci) {
        const int c = t + ci*256;
        if (c < CC) se += expf(v[ci] - m);
    }
    for (int o = 32; o > 0; o >>= 1) se += __shfl_down(se, o, 64);
    if (lane == 0) red[wid] = se;
    __syncthreads();
    if (t == 0) red[5] = m + logf(red[0] + red[1] + red[2] + red[3]);
    __syncthreads();
    const float lse = red[5];
    #pragma unroll
    for (int ci = 0; ci < 4; ++ci) {
        const int c = t + ci*256;
        if (c < CC) out[(size_t)b*CC + c] = v[ci] - lse;
    }
}

extern "C" void kernel_launch(void* const* d_in, const int* in_sizes, int n_in,
                              void* d_out, int out_size, void* d_ws, size_t ws_size,
                              hipStream_t stream) {
    const float* data = (const float*)d_in[0];
    const float* h0   = (const float*)d_in[1];
    const float* c0   = (const float*)d_in[2];
    const float* wf   = (const float*)d_in[3];
    const float* wi   = (const float*)d_in[4];
    const float* wc   = (const float*)d_in[5];
    const float* wo   = (const float*)d_in[6];
    const float* fcw  = (const float*)d_in[7];
    const float* fcb  = (const float*)d_in[8];
    float* out = (float*)d_out;

    // Config A: CH_H=64 (JCH=16), CH_D=16 (JCD=32) -> ~9.6 MB ws, 512 stage-1 blocks.
    // Config B: CH_H=8  (JCH=128), CH_D=4 (JCD=128) -> 2.36 MB ws (proven safe).
    const size_t needA = ((size_t)64*QQ + (size_t)16*BB*QQ + (size_t)BB*HH) * 4;
    const bool cfgA = (ws_size >= needA);

    float* ws = (float*)d_ws;
    if (cfgA) {
        float* hp = ws;                               // 64*QQ
        float* dp = hp + (size_t)64*QQ;               // 16*BB*QQ
        float* hl = dp + (size_t)16*BB*QQ;            // BB*HH
        k_h0part<16><<<dim3(4, 64), 256, 0, stream>>>(h0, wf, wi, wc, wo, hp);
        k_datapart<32><<<dim3(16, 16), 256, 0, stream>>>(data, wf, wi, wc, wo, dp);
        k_cell<64,16><<<dim3(HH/256, BB), 256, 0, stream>>>(hp, dp, c0, hl);
        k_fc_gemm<<<dim3(CC/FCB), 256, 0, stream>>>(hl, fcw, fcb, out);
    } else {
        float* hp = ws;                               // 8*QQ
        float* dp = hp + (size_t)8*QQ;                // 4*BB*QQ
        float* hl = dp + (size_t)4*BB*QQ;             // BB*HH
        k_h0part<128><<<dim3(4, 8), 256, 0, stream>>>(h0, wf, wi, wc, wo, hp);
        k_datapart<128><<<dim3(16, 4), 256, 0, stream>>>(data, wf, wi, wc, wo, dp);
        k_cell<8,4><<<dim3(HH/256, BB), 256, 0, stream>>>(hp, dp, c0, hl);
        k_fc_gemm<<<dim3(CC/FCB), 256, 0, stream>>>(hl, fcw, fcb, out);
    }
    k_lsm<<<dim3(BB), 256, 0, stream>>>(out);
}

// Round 5
// 42.822 us; speedup vs baseline: 1.8903x; 1.0843x over previous
//
#include <hip/hip_runtime.h>
#include <math.h>

#define BB 32
#define TT 512
#define FF 512
#define HH 1024
#define CC 1000
#define QQ (4*HH)    // 4096 gate columns
#define FCB 8        // fc columns per block

// ---------------- Stage 1 (fused): gate partials ----------------
// First 4*CHH blocks: h0 contribution (gate = bx&3, chunk = bx>>2, JCH rows).
// Next 16*CHD blocks: data[:,T-1,:] contribution (colblock = idx&15, chunk = idx>>4).
template<int JCH, int CHH, int JCD, int CHD>
__global__ __launch_bounds__(256) void k_gates(
    const float* __restrict__ data, const float* __restrict__ h0,
    const float* __restrict__ wf, const float* __restrict__ wi,
    const float* __restrict__ wc, const float* __restrict__ wo,
    float* __restrict__ hp, float* __restrict__ dp)
{
    constexpr int LDSN = (BB*JCD > JCH) ? BB*JCD : JCH;
    __shared__ float lds[LDSN];
    const int t  = threadIdx.x;
    const int bx = blockIdx.x;
    constexpr int NH = 4*CHH;

    if (bx < NH) {
        // ---- h0 part: batch-independent matvec over rows [ch*JCH, ch*JCH+JCH) ----
        const int gate = bx & 3;
        const int ch   = bx >> 2;
        const float* w = (gate==0) ? wf : (gate==1) ? wi : (gate==2) ? wc : wo;
        if (t < JCH) lds[t] = h0[ch*JCH + t];
        __syncthreads();
        const int k4 = t*4;
        float4 s = make_float4(0.f,0.f,0.f,0.f);
        #pragma unroll 16
        for (int j = 0; j < JCH; ++j) {
            const float4 wv = *(const float4*)(w + (size_t)(ch*JCH + j)*HH + k4);
            const float  hv = lds[j];
            s.x += hv*wv.x; s.y += hv*wv.y; s.z += hv*wv.z; s.w += hv*wv.w;
        }
        *(float4*)(hp + (size_t)ch*QQ + gate*HH + k4) = s;
    } else {
        // ---- data part: rows [HH + cd*JCD, ...), 256 cols per block ----
        const int idx  = bx - NH;
        const int cb   = idx & 15;            // 256-col block
        const int cd   = idx >> 4;            // j-chunk
        const int gate = cb >> 2;
        const int k0   = (cb & 3)*256;
        const float* w = (gate==0) ? wf : (gate==1) ? wi : (gate==2) ? wc : wo;
        const int jc0  = cd*JCD;

        constexpr int SL = BB*JCD/4;          // float4 slots to stage
        for (int s = t; s < SL; s += 256) {
            const int b  = s / (JCD/4);
            const int jj = (s % (JCD/4))*4;
            const float4 v = *(const float4*)(data + (size_t)b*TT*FF + (size_t)(TT-1)*FF + jc0 + jj);
            lds[b*JCD + jj+0] = v.x; lds[b*JCD + jj+1] = v.y;
            lds[b*JCD + jj+2] = v.z; lds[b*JCD + jj+3] = v.w;
        }
        __syncthreads();

        const int lane = t & 63;
        const int b0   = (t >> 6) * 8;
        const int k4   = k0 + lane*4;
        float4 acc[8];
        #pragma unroll
        for (int bi = 0; bi < 8; ++bi) acc[bi] = make_float4(0.f,0.f,0.f,0.f);

        #pragma unroll 16
        for (int j = 0; j < JCD; ++j) {
            const float4 wv = *(const float4*)(w + (size_t)(HH + jc0 + j)*HH + k4);
            #pragma unroll
            for (int bi = 0; bi < 8; ++bi) {
                const float dv = lds[(b0+bi)*JCD + j];
                acc[bi].x += dv*wv.x; acc[bi].y += dv*wv.y;
                acc[bi].z += dv*wv.z; acc[bi].w += dv*wv.w;
            }
        }
        #pragma unroll
        for (int bi = 0; bi < 8; ++bi)
            *(float4*)(dp + ((size_t)cd*BB + b0 + bi)*QQ + cb*256 + lane*4) = acc[bi];
    }
}

// ---------------- Stage 2: reduce partials + gates -> h_last ----------------
// grid = (HH/256 = 4, BB), block = 256.
template<int CH, int CD>
__global__ __launch_bounds__(256) void k_cell(
    const float* __restrict__ hp, const float* __restrict__ dp,
    const float* __restrict__ c0, float* __restrict__ hlast)
{
    __shared__ float4 p[4][64];
    const int t    = threadIdx.x;
    const int kblk = blockIdx.x;
    const int b    = blockIdx.y;
    const int g    = t >> 6;
    const int i    = t & 63;
    const int q    = g*HH + kblk*256 + i*4;

    float4 s = make_float4(0.f,0.f,0.f,0.f);
    #pragma unroll
    for (int ch = 0; ch < CH; ++ch) {
        const float4 v = *(const float4*)(hp + (size_t)ch*QQ + q);
        s.x += v.x; s.y += v.y; s.z += v.z; s.w += v.w;
    }
    #pragma unroll
    for (int cd = 0; cd < CD; ++cd) {
        const float4 v = *(const float4*)(dp + ((size_t)cd*BB + b)*QQ + q);
        s.x += v.x; s.y += v.y; s.z += v.z; s.w += v.w;
    }
    p[g][i] = s;
    __syncthreads();

    if (t < 64) {
        const float4 gf = p[0][t], gi = p[1][t], gc = p[2][t], go = p[3][t];
        const float4 cv = *(const float4*)(c0 + kblk*256 + t*4);
        float4 h;
        {
            const float f = 1.f/(1.f + expf(-gf.x)), ii = 1.f/(1.f + expf(-gi.x));
            const float cg = tanhf(gc.x), o = 1.f/(1.f + expf(-go.x));
            h.x = o*tanhf(f*cv.x + ii*cg);
        }
        {
            const float f = 1.f/(1.f + expf(-gf.y)), ii = 1.f/(1.f + expf(-gi.y));
            const float cg = tanhf(gc.y), o = 1.f/(1.f + expf(-go.y));
            h.y = o*tanhf(f*cv.y + ii*cg);
        }
        {
            const float f = 1.f/(1.f + expf(-gf.z)), ii = 1.f/(1.f + expf(-gi.z));
            const float cg = tanhf(gc.z), o = 1.f/(1.f + expf(-go.z));
            h.z = o*tanhf(f*cv.z + ii*cg);
        }
        {
            const float f = 1.f/(1.f + expf(-gf.w)), ii = 1.f/(1.f + expf(-gi.w));
            const float cg = tanhf(gc.w), o = 1.f/(1.f + expf(-go.w));
            h.w = o*tanhf(f*cv.w + ii*cg);
        }
        *(float4*)(hlast + (size_t)b*HH + kblk*256 + t*4) = h;
    }
}

// ---------------- Stage 3a: relu(h @ fc_w^T + fc_b) -> d_out ----------------
// grid = (CC/FCB = 125), block = 256.
__global__ __launch_bounds__(256) void k_fc_gemm(
    const float* __restrict__ hlast, const float* __restrict__ fcw,
    const float* __restrict__ fcb, float* __restrict__ logits)
{
    __shared__ float hs[BB][257];
    __shared__ float wl[FCB][257];
    const int t  = threadIdx.x;
    const int c0 = blockIdx.x * FCB;
    const int b  = t & 31;
    const int cl = t >> 5;
    const int c  = c0 + cl;
    float acc = 0.f;
    #pragma unroll
    for (int kc = 0; kc < HH/256; ++kc) {
        const int k0 = kc*256;
        for (int l = t; l < BB*64; l += 256) {
            const int bb = l >> 6, kk = l & 63;
            const float4 v = *(const float4*)(hlast + (size_t)bb*HH + k0 + kk*4);
            hs[bb][kk*4+0] = v.x; hs[bb][kk*4+1] = v.y;
            hs[bb][kk*4+2] = v.z; hs[bb][kk*4+3] = v.w;
        }
        for (int l = t; l < FCB*64; l += 256) {
            const int cc = l >> 6, kk = l & 63;
            const float4 v = *(const float4*)(fcw + (size_t)(c0+cc)*HH + k0 + kk*4);
            wl[cc][kk*4+0] = v.x; wl[cc][kk*4+1] = v.y;
            wl[cc][kk*4+2] = v.z; wl[cc][kk*4+3] = v.w;
        }
        __syncthreads();
        #pragma unroll 16
        for (int k = 0; k < 256; ++k)
            acc += hs[b][k] * wl[cl][k];
        __syncthreads();
    }
    logits[(size_t)b*CC + c] = fmaxf(acc + fcb[c], 0.f);
}

// ---------------- Stage 3b: log_softmax in place on d_out ----------------
// grid = (BB), block = 256.
__global__ __launch_bounds__(256) void k_lsm(float* __restrict__ out)
{
    __shared__ float red[8];
    const int b = blockIdx.x, t = threadIdx.x;
    float v[4]; float vmax = -1e30f;
    #pragma unroll
    for (int ci = 0; ci < 4; ++ci) {
        const int c = t + ci*256;
        v[ci] = (c < CC) ? out[(size_t)b*CC + c] : -1e30f;
        vmax = fmaxf(vmax, v[ci]);
    }
    for (int o = 32; o > 0; o >>= 1) vmax = fmaxf(vmax, __shfl_down(vmax, o, 64));
    const int lane = t & 63, wid = t >> 6;
    if (lane == 0) red[wid] = vmax;
    __syncthreads();
    if (t == 0) red[4] = fmaxf(fmaxf(red[0], red[1]), fmaxf(red[2], red[3]));
    __syncthreads();
    const float m = red[4];
    float se = 0.f;
    #pragma unroll
    for (int ci = 0; ci < 4; ++ci) {
        const int c = t + ci*256;
        if (c < CC) se += expf(v[ci] - m);
    }
    for (int o = 32; o > 0; o >>= 1) se += __shfl_down(se, o, 64);
    if (lane == 0) red[wid] = se;
    __syncthreads();
    if (t == 0) red[5] = m + logf(red[0] + red[1] + red[2] + red[3]);
    __syncthreads();
    const float lse = red[5];
    #pragma unroll
    for (int ci = 0; ci < 4; ++ci) {
        const int c = t + ci*256;
        if (c < CC) out[(size_t)b*CC + c] = v[ci] - lse;
    }
}

extern "C" void kernel_launch(void* const* d_in, const int* in_sizes, int n_in,
                              void* d_out, int out_size, void* d_ws, size_t ws_size,
                              hipStream_t stream) {
    const float* data = (const float*)d_in[0];
    const float* h0   = (const float*)d_in[1];
    const float* c0   = (const float*)d_in[2];
    const float* wf   = (const float*)d_in[3];
    const float* wi   = (const float*)d_in[4];
    const float* wc   = (const float*)d_in[5];
    const float* wo   = (const float*)d_in[6];
    const float* fcw  = (const float*)d_in[7];
    const float* fcb  = (const float*)d_in[8];
    float* out = (float*)d_out;

    // Config A: CH_H=64 (JCH=16), CH_D=16 (JCD=32) -> ~9.6 MB ws, 512 stage-1 blocks.
    // Config B: CH_H=8  (JCH=128), CH_D=4 (JCD=128) -> 2.36 MB ws (fallback).
    const size_t needA = ((size_t)64*QQ + (size_t)16*BB*QQ + (size_t)BB*HH) * 4;
    const bool cfgA = (ws_size >= needA);

    float* ws = (float*)d_ws;
    if (cfgA) {
        float* hp = ws;                               // 64*QQ
        float* dp = hp + (size_t)64*QQ;               // 16*BB*QQ
        float* hl = dp + (size_t)16*BB*QQ;            // BB*HH
        k_gates<16,64,32,16><<<dim3(4*64 + 16*16), 256, 0, stream>>>(data, h0, wf, wi, wc, wo, hp, dp);
        k_cell<64,16><<<dim3(HH/256, BB), 256, 0, stream>>>(hp, dp, c0, hl);
        k_fc_gemm<<<dim3(CC/FCB), 256, 0, stream>>>(hl, fcw, fcb, out);
    } else {
        float* hp = ws;                               // 8*QQ
        float* dp = hp + (size_t)8*QQ;                // 4*BB*QQ
        float* hl = dp + (size_t)4*BB*QQ;             // BB*HH
        k_gates<128,8,128,4><<<dim3(4*8 + 16*4), 256, 0, stream>>>(data, h0, wf, wi, wc, wo, hp, dp);
        k_cell<8,4><<<dim3(HH/256, BB), 256, 0, stream>>>(hp, dp, c0, hl);
        k_fc_gemm<<<dim3(CC/FCB), 256, 0, stream>>>(hl, fcw, fcb, out);
    }
    k_lsm<<<dim3(BB), 256, 0, stream>>>(out);
}